// Round 6
// baseline (670.987 us; speedup 1.0000x reference)
//
#include <hip/hip_runtime.h>

// Problem constants
#define Bq 16
#define Cq 512
#define Nq 4096
#define Hq 512

// Diagnostic: repeat each heavy kernel's (idempotent) body REP times so every
// kernel's dispatch exceeds the 80us harness fills and surfaces in the rocprof
// top-5 with full counters. Outputs are bit-identical to single-shot.
#define REP 6

typedef float f32x4 __attribute__((ext_vector_type(4)));

// ---------------------------------------------------------------------------
// K1 (pass 1 over x): 1024 blocks (b, nc, cq). Body repeated REP times.
// ---------------------------------------------------------------------------
__global__ __launch_bounds__(256) void k1_stats(const float* __restrict__ x,
                                                float* __restrict__ part_xs_n,
                                                float* __restrict__ part_xs_c){
  __shared__ float colred[4][256];
  __shared__ float rowp[4][32][64];
  int blk  = blockIdx.x;
  int b    = blk >> 6;
  int nc   = (blk >> 2) & 15;
  int cq   = blk & 3;
  int wave = threadIdx.x >> 6;
  int lane = threadIdx.x & 63;
  int t    = threadIdx.x;
  int c0   = cq*128 + wave;
  const float* p = x + ((size_t)b*Cq + c0)*Nq + (nc << 8) + (lane << 2);
  for (int rep = 0; rep < REP; ++rep){
    __syncthreads();                       // prev rep's LDS readers done
    float4 acc = {0.f,0.f,0.f,0.f};
    #pragma unroll 8
    for (int k = 0; k < 32; ++k){
      float4 v = *(const float4*)(p + (size_t)(k*4)*Nq);
      acc.x += v.x; acc.y += v.y; acc.z += v.z; acc.w += v.w;
      rowp[wave][k][lane] = (v.x + v.y) + (v.z + v.w);
    }
    *(float4*)&colred[wave][lane << 2] = acc;
    __syncthreads();
    part_xs_n[((size_t)(cq*Bq) + b)*Nq + (nc << 8) + t] =
        (colred[0][t] + colred[1][t]) + (colred[2][t] + colred[3][t]);
    if (t < 128){
      const float4* rp4 = (const float4*)&rowp[t & 3][t >> 2][0];
      float4 sv = {0.f,0.f,0.f,0.f};
      #pragma unroll
      for (int j4 = 0; j4 < 16; ++j4){
        float4 vv = rp4[(j4 + t) & 15];
        sv.x += vv.x; sv.y += vv.y; sv.z += vv.z; sv.w += vv.w;
      }
      part_xs_c[((size_t)(b*16 + nc) << 9) + cq*128 + t] =
          (sv.x + sv.y) + (sv.z + sv.w);
    }
  }
}

// ---------------------------------------------------------------------------
// K1b: tiny reduction; left single-shot (inferred as residual).
// ---------------------------------------------------------------------------
__global__ __launch_bounds__(256) void k1b_red(const float* __restrict__ part_xs_n,
                                               const float* __restrict__ part_xs_c,
                                               float* __restrict__ xs_n,
                                               float* __restrict__ xs_c){
  int blk = blockIdx.x;
  if (blk < 256){
    int i = (blk << 8) + (int)threadIdx.x;
    float acc = 0.f;
    #pragma unroll
    for (int cq=0; cq<4; ++cq) acc += part_xs_n[(size_t)cq*(Bq*Nq) + i];
    xs_n[i] = acc;
  } else {
    int j = ((blk-256) << 8) + (int)threadIdx.x;
    int b = j >> 9, c = j & 511;
    float acc = 0.f;
    #pragma unroll
    for (int nc=0; nc<16; ++nc) acc += part_xs_c[((size_t)(b*16+nc) << 9) + c];
    xs_c[j] = acc;
  }
}

// ---------------------------------------------------------------------------
// K2: s vectors. Body repeated REP times.
// ---------------------------------------------------------------------------
__global__ __launch_bounds__(256) void k2_s(const float* __restrict__ w_cf,
                                            const float* __restrict__ w_sf,
                                            const float* __restrict__ xs_n,
                                            const float* __restrict__ xs_c,
                                            float* __restrict__ s_cf,
                                            float* __restrict__ s_sf){
  __shared__ float red[4][Bq];
  int blk = blockIdx.x;
  const float* w; const float* src; float* dst; int L;
  if (blk < Hq) { w = w_cf + (size_t)blk*Nq; src = xs_n; dst = s_cf; L = Nq; }
  else          { w = w_sf + (size_t)(blk-Hq)*Cq; src = xs_c; dst = s_sf; L = Cq; }
  int h = blk & (Hq-1);
  int t = threadIdx.x;
  int wave = t >> 6, lane = t & 63;
  for (int rep = 0; rep < REP; ++rep){
    __syncthreads();
    float acc[Bq];
    #pragma unroll
    for (int b=0;b<Bq;b++) acc[b]=0.f;
    for (int i0 = t*4; i0 < L; i0 += 1024){
      float4 wv = *(const float4*)(w + i0);
      #pragma unroll
      for (int b=0;b<Bq;b++){
        float4 sv = *(const float4*)(src + (size_t)b*L + i0);
        acc[b] += wv.x*sv.x + wv.y*sv.y + wv.z*sv.z + wv.w*sv.w;
      }
    }
    #pragma unroll
    for (int b=0;b<Bq;b++){
      float v = acc[b];
      #pragma unroll
      for (int off=32; off; off>>=1) v += __shfl_down(v, off, 64);
      if (lane == 0) red[wave][b] = v;
    }
    __syncthreads();
    if (t < Bq)
      dst[(size_t)t*Hq + h] = (red[0][t]+red[1][t])+(red[2][t]+red[3][t]);
  }
}

// ---------------------------------------------------------------------------
// K3: v partial products. Compute+store repeated REP times (sl is read-only).
// ---------------------------------------------------------------------------
__global__ __launch_bounds__(256) void k3_v(const float* __restrict__ w_cg,
                                            const float* __restrict__ w_sg,
                                            const float* __restrict__ s_cf,
                                            const float* __restrict__ s_sf,
                                            float* __restrict__ part_cg,
                                            float* __restrict__ part_sg){
  __shared__ float sl[8*64];
  int blk = blockIdx.x;
  const float* w; const float* s; float* dst; int L, jc, hc, bh;
  if (blk < 256){ w=w_cg; s=s_cf; dst=part_cg; L=Nq;
    jc = blk >> 4; hc = (blk >> 1) & 7; bh = blk & 1; }
  else { int k = blk - 256; w=w_sg; s=s_sf; dst=part_sg; L=Cq;
    jc = k >> 4; hc = (k >> 1) & 7; bh = k & 1; }
  int h0 = hc*64, b0 = bh*8;
  for (int i = threadIdx.x; i < 8*64; i += 256){
    int bb = i >> 6, hh = i & 63;
    sl[i] = s[(b0+bb)*Hq + h0 + hh];
  }
  __syncthreads();
  int j = (jc<<8) + (int)threadIdx.x;
  for (int rep = 0; rep < REP; ++rep){
    float acc[8];
    #pragma unroll
    for (int bb=0;bb<8;bb++) acc[bb]=0.f;
    #pragma unroll 8
    for (int hh=0; hh<64; ++hh){
      float wv = w[(size_t)(h0+hh)*L + j];
      #pragma unroll
      for (int bb=0;bb<8;bb++) acc[bb] += sl[bb*64+hh]*wv;
    }
    #pragma unroll
    for (int bb=0;bb<8;bb++)
      dst[((size_t)hc*Bq + (b0+bb))*L + j] = acc[bb];
  }
}

// ---------------------------------------------------------------------------
// K4 (pass 2 over x): preamble once; x-pass body repeated REP times.
// ---------------------------------------------------------------------------
__global__ __launch_bounds__(256) void k4_comp(const float* __restrict__ x,
                                               const float* __restrict__ part_cg,
                                               const float* __restrict__ part_sg,
                                               float* __restrict__ part_sp,
                                               float* __restrict__ part_ch){
  __shared__ float colred[4][256];
  __shared__ float rowp[4][32][64];
  __shared__ float vs[128];
  int blk  = blockIdx.x;
  int b    = blk >> 6;
  int nc   = (blk >> 2) & 15;
  int cq   = blk & 3;
  int wave = threadIdx.x >> 6;
  int lane = threadIdx.x & 63;
  int t    = threadIdx.x;
  if (t < 128){
    int c = cq*128 + t;
    float a = 0.f;
    #pragma unroll
    for (int hc=0; hc<8; ++hc) a += part_sg[((size_t)hc*Bq + b)*Cq + c];
    vs[t] = a;
  }
  float4 g = {0.f,0.f,0.f,0.f};
  {
    size_t off = (size_t)b*Nq + (nc << 8) + (lane << 2);
    #pragma unroll
    for (int hc=0; hc<8; ++hc){
      float4 pgv = *(const float4*)(part_cg + (size_t)hc*(Bq*Nq) + off);
      g.x += pgv.x; g.y += pgv.y; g.z += pgv.z; g.w += pgv.w;
    }
  }
  __syncthreads();
  int c0 = cq*128 + wave;
  const float* p = x + ((size_t)b*Cq + c0)*Nq + (nc << 8) + (lane << 2);
  for (int rep = 0; rep < REP; ++rep){
    __syncthreads();
    float4 acc = {0.f,0.f,0.f,0.f};
    #pragma unroll 8
    for (int k = 0; k < 32; ++k){
      float4 v = *(const float4*)(p + (size_t)(k*4)*Nq);
      float s = vs[wave + k*4];
      acc.x += v.x*s; acc.y += v.y*s; acc.z += v.z*s; acc.w += v.w*s;
      rowp[wave][k][lane] = v.x*g.x + v.y*g.y + v.z*g.z + v.w*g.w;
    }
    *(float4*)&colred[wave][lane << 2] = acc;
    __syncthreads();
    part_sp[((size_t)(cq*Bq) + b)*Nq + (nc << 8) + t] =
        (colred[0][t] + colred[1][t]) + (colred[2][t] + colred[3][t]);
    if (t < 128){
      const float4* rp4 = (const float4*)&rowp[t & 3][t >> 2][0];
      float4 sv = {0.f,0.f,0.f,0.f};
      #pragma unroll
      for (int j4 = 0; j4 < 16; ++j4){
        float4 vv = rp4[(j4 + t) & 15];
        sv.x += vv.x; sv.y += vv.y; sv.z += vv.z; sv.w += vv.w;
      }
      part_ch[((size_t)(b*16 + nc) << 9) + cq*128 + t] =
          (sv.x + sv.y) + (sv.z + sv.w);
    }
  }
}

// ---------------------------------------------------------------------------
// K5: softmax; single-shot (small).
// ---------------------------------------------------------------------------
__global__ __launch_bounds__(256) void k5_softmax(const float* __restrict__ part_ch,
                                                  const float* __restrict__ part_sp,
                                                  float* __restrict__ out){
  __shared__ float buf[Nq];
  __shared__ float lds[4];
  __shared__ float bcast;
  int blk = blockIdx.x;
  int t = threadIdx.x;
  float* dst; int L;
  const size_t OUT0 = (size_t)Bq*Cq*Nq;
  if (blk < Bq){
    int b = blk; L = Cq;
    for (int c = t; c < Cq; c += 256){
      float s = 0.f;
      #pragma unroll
      for (int nc=0; nc<16; ++nc) s += part_ch[((size_t)(b*16+nc) << 9) + c];
      buf[c] = s;
    }
    dst = out + OUT0 + (size_t)b*Cq;
  } else {
    int b = blk - Bq; L = Nq;
    for (int n = t; n < Nq; n += 256){
      float s = 0.f;
      #pragma unroll
      for (int cq=0; cq<4; ++cq) s += part_sp[((size_t)(cq*Bq)+b)*Nq + n];
      buf[n] = s;
    }
    dst = out + OUT0 + (size_t)Bq*Cq + (size_t)b*Nq;
  }
  __syncthreads();
  float m = -3.4e38f;
  for (int i=t;i<L;i+=256) m = fmaxf(m, buf[i]);
  #pragma unroll
  for (int off=32; off; off>>=1) m = fmaxf(m, __shfl_down(m, off, 64));
  if ((t&63)==0) lds[t>>6]=m;
  __syncthreads();
  if (t==0) bcast = fmaxf(fmaxf(lds[0],lds[1]),fmaxf(lds[2],lds[3]));
  __syncthreads();
  m = bcast;
  float ssum=0.f;
  for (int i=t;i<L;i+=256) ssum += __expf(buf[i]-m);
  #pragma unroll
  for (int off=32; off; off>>=1) ssum += __shfl_down(ssum, off, 64);
  __syncthreads();
  if ((t&63)==0) lds[t>>6]=ssum;
  __syncthreads();
  if (t==0) bcast = 1.f/((lds[0]+lds[1])+(lds[2]+lds[3]));
  __syncthreads();
  float inv = bcast;
  for (int i=t;i<L;i+=256) dst[i] = __expf(buf[i]-m)*inv;
}

// ---------------------------------------------------------------------------
// K6: out = x*cm*sm. Body repeated REP times (idempotent; masks untouched).
// ---------------------------------------------------------------------------
__global__ __launch_bounds__(256) void k6_out(const float* __restrict__ x,
                                              float* __restrict__ out){
  const size_t OUT0 = (size_t)Bq*Cq*Nq;
  const float* cm = out + OUT0;
  const float* sm = out + OUT0 + (size_t)Bq*Cq;
  int blk = blockIdx.x;              // b*512 + c
  int b = blk >> 9;
  size_t rowoff = (size_t)blk * Nq;
  float cmv = cm[blk];
  const float* sp = sm + (size_t)b*Nq;
  int t = threadIdx.x;
  for (int rep = 0; rep < REP; ++rep){
    #pragma unroll
    for (int q = 0; q < 4; ++q){
      int n0 = q*1024 + t*4;
      float4 xv = *(const float4*)(x + rowoff + n0);
      float4 sv = *(const float4*)(sp + n0);
      f32x4 o;
      o.x = xv.x*cmv*sv.x; o.y = xv.y*cmv*sv.y;
      o.z = xv.z*cmv*sv.z; o.w = xv.w*cmv*sv.w;
      __builtin_nontemporal_store(o, (f32x4*)(out + rowoff + n0));
    }
  }
}

extern "C" void kernel_launch(void* const* d_in, const int* in_sizes, int n_in,
                              void* d_out, int out_size, void* d_ws, size_t ws_size,
                              hipStream_t stream){
  const float* x    = (const float*)d_in[0];
  const float* w_cf = (const float*)d_in[1];
  const float* w_cg = (const float*)d_in[2];
  const float* w_sf = (const float*)d_in[3];
  const float* w_sg = (const float*)d_in[4];
  float* out = (float*)d_out;

  float* ws = (float*)d_ws;
  float* xs_n = ws;                  // B*N   = 65536
  float* xs_c = xs_n + Bq*Nq;        // B*C   = 8192
  float* s_cf = xs_c + Bq*Cq;        // B*H   = 8192
  float* s_sf = s_cf + Bq*Hq;        // B*H   = 8192
  float* arenaA = s_sf + Bq*Hq;
  float* part_xs_n = arenaA;                    // 4*B*N  (k1 -> k1b)
  float* part_xs_c = arenaA + 4*Bq*Nq;          // 16*B*C (k1 -> k1b)
  float* part_cg   = arenaA;                    // 8*B*N  (k3 -> k4)
  float* part_sg   = arenaA + 8*Bq*Nq;          // 8*B*C  (k3 -> k4)
  float* arenaB = arenaA + 8*Bq*Nq + 8*Bq*Cq;
  float* part_sp   = arenaB;                    // 4*B*N  (k4 -> k5)
  float* part_ch   = arenaB + 4*Bq*Nq;          // 16*B*C (k4 -> k5)

  k1_stats  <<<1024,  256, 0, stream>>>(x, part_xs_n, part_xs_c);
  k1b_red   <<<288,   256, 0, stream>>>(part_xs_n, part_xs_c, xs_n, xs_c);
  k2_s      <<<2*Hq,  256, 0, stream>>>(w_cf, w_sf, xs_n, xs_c, s_cf, s_sf);
  k3_v      <<<288,   256, 0, stream>>>(w_cg, w_sg, s_cf, s_sf, part_cg, part_sg);
  k4_comp   <<<1024,  256, 0, stream>>>(x, part_cg, part_sg, part_sp, part_ch);
  k5_softmax<<<2*Bq,  256, 0, stream>>>(part_ch, part_sp, out);
  k6_out    <<<Bq*Cq, 256, 0, stream>>>(x, out);
}

// Round 8
// 586.580 us; speedup vs baseline: 1.1439x; 1.1439x over previous
//
#include <hip/hip_runtime.h>

// Problem constants
#define Bq 16
#define Cq 512
#define Nq 4096
#define Hq 512

typedef float f32x4 __attribute__((ext_vector_type(4)));

// workspace float offsets
#define O_XSN 0
#define O_XSC (O_XSN + Bq*Nq)
#define O_SCF (O_XSC + Bq*Cq)
#define O_SSF (O_SCF + Bq*Hq)
#define O_ARA (O_SSF + Bq*Hq)
#define O_PXN (O_ARA)                     // part_xs_n [4][B][N]
#define O_PXC (O_ARA + 4*Bq*Nq)           // part_xs_c [B*16][C]
#define O_PCG (O_ARA)                     // part_cg   [8][B][N] (after K1' done)
#define O_PSG (O_ARA + 8*Bq*Nq)           // part_sg   [8][B][C]
#define O_ARB (O_ARA + 8*Bq*Nq + 8*Bq*Cq)
#define O_PSP (O_ARB)                     // part_sp   [4][B][N]
#define O_PCH (O_ARB + 4*Bq*Nq)           // part_ch   [B*16][C]
#define O_CNT (O_ARB + 4*Bq*Nq + 16*Bq*Cq) // 336 ints: 256 (b,nc) + 64 (b,cq) + 16 (b)

// ---------------------------------------------------------------------------
// K1' : x-pass 1 -> partials; ticket groups finish xs_n / xs_c in-kernel.
// NO WAITING anywhere: last ticket does bounded extra work. Deadlock-free.
// ---------------------------------------------------------------------------
__global__ __launch_bounds__(256) void k1_stats(const float* __restrict__ x,
                                                float* part_xs_n,
                                                float* part_xs_c,
                                                float* __restrict__ xs_n,
                                                float* __restrict__ xs_c,
                                                int* cnt){
  __shared__ float colred[1024];
  __shared__ int tik_n, tik_c;
  int blk  = blockIdx.x;
  int b    = blk >> 6;
  int nc   = (blk >> 2) & 15;
  int cq   = blk & 3;
  int t    = threadIdx.x;
  int wave = t >> 6;
  int lane = t & 63;
  int c0   = cq*128 + wave;
  const float* p = x + ((size_t)b*Cq + c0)*Nq + (nc << 8) + (lane << 2);
  float* pc = part_xs_c + ((size_t)(b*16 + nc) << 9) + c0;
  float4 acc = {0.f,0.f,0.f,0.f};
  #pragma unroll 8
  for (int k = 0; k < 32; ++k){
    float4 v = *(const float4*)(p + (size_t)(k*4)*Nq);
    acc.x += v.x; acc.y += v.y; acc.z += v.z; acc.w += v.w;
    float r = (v.x + v.y) + (v.z + v.w);
    #pragma unroll
    for (int off=32; off; off>>=1) r += __shfl_down(r, off, 64);
    if (lane == 0) pc[k*4] = r;
  }
  *(float4*)&colred[(wave<<8) + (lane<<2)] = acc;
  __syncthreads();
  part_xs_n[((size_t)(cq*Bq) + b)*Nq + (nc << 8) + t] =
      (colred[t] + colred[256+t]) + (colred[512+t] + colred[768+t]);

  // ---- ticket + last-block finishers (no spin) ----
  __threadfence();                                    // release partial stores
  if (t == 0){
    tik_n = atomicAdd(&cnt[b*16 + nc], 1);            // group over cq (4)
    tik_c = atomicAdd(&cnt[256 + b*4 + cq], 1);       // group over nc (16)
  }
  __syncthreads();
  if (tik_n == 3){                                    // last of 4 -> xs_n slice
    __threadfence();                                  // acquire
    int i = b*Nq + (nc << 8) + t;
    float a = 0.f;
    #pragma unroll
    for (int q = 0; q < 4; ++q) a += part_xs_n[(size_t)q*(Bq*Nq) + i];
    xs_n[i] = a;
  }
  if (tik_c == 15 && t < 128){                        // last of 16 -> xs_c slice
    __threadfence();
    int c = cq*128 + t;
    float a = 0.f;
    #pragma unroll
    for (int q = 0; q < 16; ++q) a += part_xs_c[((size_t)(b*16 + q) << 9) + c];
    xs_c[b*Cq + c] = a;
  }
}

// ---------------------------------------------------------------------------
// K2: s_cf[b,h] / s_sf[b,h] (unchanged, proven).
// ---------------------------------------------------------------------------
__global__ __launch_bounds__(256) void k2_s(const float* __restrict__ w_cf,
                                            const float* __restrict__ w_sf,
                                            const float* __restrict__ xs_n,
                                            const float* __restrict__ xs_c,
                                            float* __restrict__ s_cf,
                                            float* __restrict__ s_sf){
  __shared__ float red[4][Bq];
  int blk = blockIdx.x;
  const float* w; const float* src; float* dst; int L;
  if (blk < Hq) { w = w_cf + (size_t)blk*Nq; src = xs_n; dst = s_cf; L = Nq; }
  else          { w = w_sf + (size_t)(blk-Hq)*Cq; src = xs_c; dst = s_sf; L = Cq; }
  int h = blk & (Hq-1);
  int t = threadIdx.x;
  int wave = t >> 6, lane = t & 63;
  float acc[Bq];
  #pragma unroll
  for (int b=0;b<Bq;b++) acc[b]=0.f;
  for (int i0 = t*4; i0 < L; i0 += 1024){
    float4 wv = *(const float4*)(w + i0);
    #pragma unroll
    for (int b=0;b<Bq;b++){
      float4 sv = *(const float4*)(src + (size_t)b*L + i0);
      acc[b] += wv.x*sv.x + wv.y*sv.y + wv.z*sv.z + wv.w*sv.w;
    }
  }
  #pragma unroll
  for (int b=0;b<Bq;b++){
    float v = acc[b];
    #pragma unroll
    for (int off=32; off; off>>=1) v += __shfl_down(v, off, 64);
    if (lane == 0) red[wave][b] = v;
  }
  __syncthreads();
  if (t < Bq)
    dst[(size_t)t*Hq + h] = (red[0][t]+red[1][t])+(red[2][t]+red[3][t]);
}

// ---------------------------------------------------------------------------
// K3: v partial products (unchanged, proven).
// ---------------------------------------------------------------------------
__global__ __launch_bounds__(256) void k3_v(const float* __restrict__ w_cg,
                                            const float* __restrict__ w_sg,
                                            const float* __restrict__ s_cf,
                                            const float* __restrict__ s_sf,
                                            float* __restrict__ part_cg,
                                            float* __restrict__ part_sg){
  __shared__ float sl[8*64];
  int blk = blockIdx.x;
  const float* w; const float* s; float* dst; int L, jc, hc, bh;
  if (blk < 256){ w=w_cg; s=s_cf; dst=part_cg; L=Nq;
    jc = blk >> 4; hc = (blk >> 1) & 7; bh = blk & 1; }
  else { int k = blk - 256; w=w_sg; s=s_sf; dst=part_sg; L=Cq;
    jc = k >> 4; hc = (k >> 1) & 7; bh = k & 1; }
  int h0 = hc*64, b0 = bh*8;
  for (int i = threadIdx.x; i < 8*64; i += 256){
    int bb = i >> 6, hh = i & 63;
    sl[i] = s[(b0+bb)*Hq + h0 + hh];
  }
  __syncthreads();
  int j = (jc<<8) + (int)threadIdx.x;
  float acc[8];
  #pragma unroll
  for (int bb=0;bb<8;bb++) acc[bb]=0.f;
  #pragma unroll 8
  for (int hh=0; hh<64; ++hh){
    float wv = w[(size_t)(h0+hh)*L + j];
    #pragma unroll
    for (int bb=0;bb<8;bb++) acc[bb] += sl[bb*64+hh]*wv;
  }
  #pragma unroll
  for (int bb=0;bb<8;bb++)
    dst[((size_t)hc*Bq + (b0+bb))*L + j] = acc[bb];
}

// ---------------------------------------------------------------------------
// K4' : x-pass 2 -> part_sp/part_ch; last block per b runs BOTH softmaxes
// (mirrors k5 exactly) and writes the masks to the out tail. No spin.
// ---------------------------------------------------------------------------
__global__ __launch_bounds__(256) void k4_comp(const float* __restrict__ x,
                                               const float* __restrict__ part_cg,
                                               const float* __restrict__ part_sg,
                                               float* part_sp,
                                               float* part_ch,
                                               float* __restrict__ out,
                                               int* cnt){
  __shared__ float smem[4224];   // body: colred[1024]+vs[128]; finisher: buf[4096]+lds4[4]+bcast
  __shared__ int tik;
  int blk  = blockIdx.x;
  int b    = blk >> 6;
  int nc   = (blk >> 2) & 15;
  int cq   = blk & 3;
  int t    = threadIdx.x;
  int wave = t >> 6;
  int lane = t & 63;
  const size_t OUT0 = (size_t)Bq*Cq*Nq;
  // ---- body (verbatim proven k4) ----
  {
    float* colred = smem;
    float* vs     = smem + 1024;
    if (t < 128){
      int c = cq*128 + t;
      float a = 0.f;
      #pragma unroll
      for (int hc=0; hc<8; ++hc) a += part_sg[((size_t)hc*Bq + b)*Cq + c];
      vs[t] = a;
    }
    float4 g = {0.f,0.f,0.f,0.f};
    {
      size_t off = (size_t)b*Nq + (nc << 8) + (lane << 2);
      #pragma unroll
      for (int hc=0; hc<8; ++hc){
        float4 pgv = *(const float4*)(part_cg + (size_t)hc*(Bq*Nq) + off);
        g.x += pgv.x; g.y += pgv.y; g.z += pgv.z; g.w += pgv.w;
      }
    }
    __syncthreads();
    int c0 = cq*128 + wave;
    const float* p = x + ((size_t)b*Cq + c0)*Nq + (nc << 8) + (lane << 2);
    float* pch = part_ch + ((size_t)(b*16 + nc) << 9) + c0;
    float4 acc = {0.f,0.f,0.f,0.f};
    #pragma unroll 8
    for (int k = 0; k < 32; ++k){
      float4 v = *(const float4*)(p + (size_t)(k*4)*Nq);
      float s = vs[wave + k*4];
      acc.x += v.x*s; acc.y += v.y*s; acc.z += v.z*s; acc.w += v.w*s;
      float r = v.x*g.x + v.y*g.y + v.z*g.z + v.w*g.w;
      #pragma unroll
      for (int off=32; off; off>>=1) r += __shfl_down(r, off, 64);
      if (lane == 0) pch[k*4] = r;
    }
    *(float4*)&colred[(wave<<8) + (lane<<2)] = acc;
    __syncthreads();
    part_sp[((size_t)(cq*Bq) + b)*Nq + (nc << 8) + t] =
        (colred[t] + colred[256+t]) + (colred[512+t] + colred[768+t]);
  }
  // ---- ticket + last-block mask finisher ----
  __threadfence();                                    // release
  if (t == 0) tik = atomicAdd(&cnt[320 + b], 1);      // group over (nc,cq): 64
  __syncthreads();
  if (tik == 63){
    __threadfence();                                  // acquire
    float* buf   = smem;
    float* lds4  = smem + 4096;
    float* bcast = smem + 4100;
    // ---- spatial softmax (L=4096), mirrors k5 ----
    for (int n = t; n < Nq; n += 256){
      float s = 0.f;
      #pragma unroll
      for (int q=0; q<4; ++q) s += part_sp[((size_t)(q*Bq)+b)*Nq + n];
      buf[n] = s;
    }
    __syncthreads();
    {
      float* dst = out + OUT0 + (size_t)Bq*Cq + (size_t)b*Nq;
      float m = -3.4e38f;
      for (int i=t;i<Nq;i+=256) m = fmaxf(m, buf[i]);
      #pragma unroll
      for (int off=32; off; off>>=1) m = fmaxf(m, __shfl_down(m, off, 64));
      if ((t&63)==0) lds4[t>>6]=m;
      __syncthreads();
      if (t==0) bcast[0] = fmaxf(fmaxf(lds4[0],lds4[1]),fmaxf(lds4[2],lds4[3]));
      __syncthreads();
      m = bcast[0];
      float ssum=0.f;
      for (int i=t;i<Nq;i+=256) ssum += __expf(buf[i]-m);
      #pragma unroll
      for (int off=32; off; off>>=1) ssum += __shfl_down(ssum, off, 64);
      __syncthreads();
      if ((t&63)==0) lds4[t>>6]=ssum;
      __syncthreads();
      if (t==0) bcast[0] = 1.f/((lds4[0]+lds4[1])+(lds4[2]+lds4[3]));
      __syncthreads();
      float inv = bcast[0];
      for (int i=t;i<Nq;i+=256) dst[i] = __expf(buf[i]-m)*inv;
    }
    __syncthreads();
    // ---- channel softmax (L=512), mirrors k5 ----
    for (int c = t; c < Cq; c += 256){
      float s = 0.f;
      #pragma unroll
      for (int q=0; q<16; ++q) s += part_ch[((size_t)(b*16+q) << 9) + c];
      buf[c] = s;
    }
    __syncthreads();
    {
      float* dst = out + OUT0 + (size_t)b*Cq;
      float m = -3.4e38f;
      for (int i=t;i<Cq;i+=256) m = fmaxf(m, buf[i]);
      #pragma unroll
      for (int off=32; off; off>>=1) m = fmaxf(m, __shfl_down(m, off, 64));
      if ((t&63)==0) lds4[t>>6]=m;
      __syncthreads();
      if (t==0) bcast[0] = fmaxf(fmaxf(lds4[0],lds4[1]),fmaxf(lds4[2],lds4[3]));
      __syncthreads();
      m = bcast[0];
      float ssum=0.f;
      for (int i=t;i<Cq;i+=256) ssum += __expf(buf[i]-m);
      #pragma unroll
      for (int off=32; off; off>>=1) ssum += __shfl_down(ssum, off, 64);
      __syncthreads();
      if ((t&63)==0) lds4[t>>6]=ssum;
      __syncthreads();
      if (t==0) bcast[0] = 1.f/((lds4[0]+lds4[1])+(lds4[2]+lds4[3]));
      __syncthreads();
      float inv = bcast[0];
      for (int i=t;i<Cq;i+=256) dst[i] = __expf(buf[i]-m)*inv;
    }
  }
}

// ---------------------------------------------------------------------------
// K6: out = x*cm*sm (unchanged, proven; ~80% HBM peak in REP probe).
// ---------------------------------------------------------------------------
__global__ __launch_bounds__(256) void k6_out(const float* __restrict__ x,
                                              float* __restrict__ out){
  const size_t OUT0 = (size_t)Bq*Cq*Nq;
  const float* cm = out + OUT0;
  const float* sm = out + OUT0 + (size_t)Bq*Cq;
  int blk = blockIdx.x;              // b*512 + c
  int b = blk >> 9;
  size_t rowoff = (size_t)blk * Nq;
  float cmv = cm[blk];
  const float* sp = sm + (size_t)b*Nq;
  int t = threadIdx.x;
  #pragma unroll
  for (int q = 0; q < 4; ++q){
    int n0 = q*1024 + t*4;
    float4 xv = *(const float4*)(x + rowoff + n0);
    float4 sv = *(const float4*)(sp + n0);
    f32x4 o;
    o.x = xv.x*cmv*sv.x; o.y = xv.y*cmv*sv.y;
    o.z = xv.z*cmv*sv.z; o.w = xv.w*cmv*sv.w;
    __builtin_nontemporal_store(o, (f32x4*)(out + rowoff + n0));
  }
}

extern "C" void kernel_launch(void* const* d_in, const int* in_sizes, int n_in,
                              void* d_out, int out_size, void* d_ws, size_t ws_size,
                              hipStream_t stream){
  const float* x    = (const float*)d_in[0];
  const float* w_cf = (const float*)d_in[1];
  const float* w_cg = (const float*)d_in[2];
  const float* w_sf = (const float*)d_in[3];
  const float* w_sg = (const float*)d_in[4];
  float* out = (float*)d_out;
  float* ws  = (float*)d_ws;

  float* xs_n      = ws + O_XSN;
  float* xs_c      = ws + O_XSC;
  float* s_cf      = ws + O_SCF;
  float* s_sf      = ws + O_SSF;
  float* part_xs_n = ws + O_PXN;
  float* part_xs_c = ws + O_PXC;
  float* part_cg   = ws + O_PCG;
  float* part_sg   = ws + O_PSG;
  float* part_sp   = ws + O_PSP;
  float* part_ch   = ws + O_PCH;
  int*   cnt       = (int*)(ws + O_CNT);   // 336 counters

  hipMemsetAsync(cnt, 0, 336*sizeof(int), stream);
  k1_stats<<<1024,  256, 0, stream>>>(x, part_xs_n, part_xs_c, xs_n, xs_c, cnt);
  k2_s    <<<2*Hq,  256, 0, stream>>>(w_cf, w_sf, xs_n, xs_c, s_cf, s_sf);
  k3_v    <<<288,   256, 0, stream>>>(w_cg, w_sg, s_cf, s_sf, part_cg, part_sg);
  k4_comp <<<1024,  256, 0, stream>>>(x, part_cg, part_sg, part_sp, part_ch, out, cnt);
  k6_out  <<<Bq*Cq, 256, 0, stream>>>(x, out);
}

// Round 9
// 322.317 us; speedup vs baseline: 2.0818x; 1.8199x over previous
//
#include <hip/hip_runtime.h>

// Problem constants
#define Bq 16
#define Cq 512
#define Nq 4096
#define Hq 512

typedef float f32x4 __attribute__((ext_vector_type(4)));

// ---------------------------------------------------------------------------
// K1 (pass 1 over x): 1024 blocks (b, nc, cq). Shuffle row-reduce (proven 322us).
// ---------------------------------------------------------------------------
__global__ __launch_bounds__(256) void k1_stats(const float* __restrict__ x,
                                                float* __restrict__ part_xs_n,
                                                float* __restrict__ part_xs_c){
  __shared__ float red[4][256];
  int blk  = blockIdx.x;
  int b    = blk >> 6;
  int nc   = (blk >> 2) & 15;
  int cq   = blk & 3;
  int wave = threadIdx.x >> 6;
  int lane = threadIdx.x & 63;
  int c0   = cq*128 + wave;
  const float* p = x + ((size_t)b*Cq + c0)*Nq + (nc << 8) + (lane << 2);
  float* pc = part_xs_c + ((size_t)(b*16 + nc) << 9) + c0;
  float4 acc = {0.f,0.f,0.f,0.f};
  #pragma unroll 8
  for (int k = 0; k < 32; ++k){
    float4 v = *(const float4*)(p + (size_t)(k*4)*Nq);
    acc.x += v.x; acc.y += v.y; acc.z += v.z; acc.w += v.w;
    float r = (v.x + v.y) + (v.z + v.w);
    #pragma unroll
    for (int off=32; off; off>>=1) r += __shfl_down(r, off, 64);
    if (lane == 0) pc[k*4] = r;
  }
  *(float4*)&red[wave][lane << 2] = acc;
  __syncthreads();
  int t = threadIdx.x;
  part_xs_n[((size_t)(cq*Bq) + b)*Nq + (nc << 8) + t] =
      (red[0][t] + red[1][t]) + (red[2][t] + red[3][t]);
}

// ---------------------------------------------------------------------------
// K1b: xs_n = sum_cq part_xs_n ; xs_c = sum_nc part_xs_c (proven).
// ---------------------------------------------------------------------------
__global__ __launch_bounds__(256) void k1b_red(const float* __restrict__ part_xs_n,
                                               const float* __restrict__ part_xs_c,
                                               float* __restrict__ xs_n,
                                               float* __restrict__ xs_c){
  int blk = blockIdx.x;
  if (blk < 256){
    int i = (blk << 8) + (int)threadIdx.x;
    float acc = 0.f;
    #pragma unroll
    for (int cq=0; cq<4; ++cq) acc += part_xs_n[(size_t)cq*(Bq*Nq) + i];
    xs_n[i] = acc;
  } else {
    int j = ((blk-256) << 8) + (int)threadIdx.x;
    int b = j >> 9, c = j & 511;
    float acc = 0.f;
    #pragma unroll
    for (int nc=0; nc<16; ++nc) acc += part_xs_c[((size_t)(b*16+nc) << 9) + c];
    xs_c[j] = acc;
  }
}

// ---------------------------------------------------------------------------
// K2: s_cf[b,h] / s_sf[b,h] (proven).
// ---------------------------------------------------------------------------
__global__ __launch_bounds__(256) void k2_s(const float* __restrict__ w_cf,
                                            const float* __restrict__ w_sf,
                                            const float* __restrict__ xs_n,
                                            const float* __restrict__ xs_c,
                                            float* __restrict__ s_cf,
                                            float* __restrict__ s_sf){
  __shared__ float red[4][Bq];
  int blk = blockIdx.x;
  const float* w; const float* src; float* dst; int L;
  if (blk < Hq) { w = w_cf + (size_t)blk*Nq; src = xs_n; dst = s_cf; L = Nq; }
  else          { w = w_sf + (size_t)(blk-Hq)*Cq; src = xs_c; dst = s_sf; L = Cq; }
  int h = blk & (Hq-1);
  int t = threadIdx.x;
  int wave = t >> 6, lane = t & 63;
  float acc[Bq];
  #pragma unroll
  for (int b=0;b<Bq;b++) acc[b]=0.f;
  for (int i0 = t*4; i0 < L; i0 += 1024){
    float4 wv = *(const float4*)(w + i0);
    #pragma unroll
    for (int b=0;b<Bq;b++){
      float4 sv = *(const float4*)(src + (size_t)b*L + i0);
      acc[b] += wv.x*sv.x + wv.y*sv.y + wv.z*sv.z + wv.w*sv.w;
    }
  }
  #pragma unroll
  for (int b=0;b<Bq;b++){
    float v = acc[b];
    #pragma unroll
    for (int off=32; off; off>>=1) v += __shfl_down(v, off, 64);
    if (lane == 0) red[wave][b] = v;
  }
  __syncthreads();
  if (t < Bq)
    dst[(size_t)t*Hq + h] = (red[0][t]+red[1][t])+(red[2][t]+red[3][t]);
}

// ---------------------------------------------------------------------------
// K3: v partial products over 64-h chunks (proven).
// ---------------------------------------------------------------------------
__global__ __launch_bounds__(256) void k3_v(const float* __restrict__ w_cg,
                                            const float* __restrict__ w_sg,
                                            const float* __restrict__ s_cf,
                                            const float* __restrict__ s_sf,
                                            float* __restrict__ part_cg,
                                            float* __restrict__ part_sg){
  __shared__ float sl[Bq*64];
  int blk = blockIdx.x;
  const float* w; const float* s; float* dst; int L, jc, hc;
  if (blk < 128){ w=w_cg; s=s_cf; dst=part_cg; L=Nq; jc=blk>>3; hc=blk&7; }
  else { int k=blk-128; w=w_sg; s=s_sf; dst=part_sg; L=Cq; jc=k>>3; hc=k&7; }
  int h0 = hc*64;
  for (int i = threadIdx.x; i < Bq*64; i += 256){
    int b = i >> 6, hh = i & 63;
    sl[i] = s[b*Hq + h0 + hh];
  }
  __syncthreads();
  int j = (jc<<8) + (int)threadIdx.x;
  float acc[Bq];
  #pragma unroll
  for (int b=0;b<Bq;b++) acc[b]=0.f;
  for (int hh=0; hh<64; ++hh){
    float wv = w[(size_t)(h0+hh)*L + j];
    #pragma unroll
    for (int b=0;b<Bq;b++) acc[b] += sl[b*64+hh]*wv;
  }
  #pragma unroll
  for (int b=0;b<Bq;b++) dst[((size_t)hc*Bq + b)*L + j] = acc[b];
}

// ---------------------------------------------------------------------------
// K4 (pass 2 over x, inline v reduce, shuffle row-reduce — proven 322us).
// ---------------------------------------------------------------------------
__global__ __launch_bounds__(256) void k4_comp(const float* __restrict__ x,
                                               const float* __restrict__ part_cg,
                                               const float* __restrict__ part_sg,
                                               float* __restrict__ part_sp,
                                               float* __restrict__ part_ch){
  __shared__ float red[4][256];
  __shared__ float vs[128];
  int blk  = blockIdx.x;
  int b    = blk >> 6;
  int nc   = (blk >> 2) & 15;
  int cq   = blk & 3;
  int wave = threadIdx.x >> 6;
  int lane = threadIdx.x & 63;
  int t    = threadIdx.x;
  if (t < 128){
    int c = cq*128 + t;
    float a = 0.f;
    #pragma unroll
    for (int hc=0; hc<8; ++hc) a += part_sg[((size_t)hc*Bq + b)*Cq + c];
    vs[t] = a;
  }
  float4 g = {0.f,0.f,0.f,0.f};
  {
    size_t off = (size_t)b*Nq + (nc << 8) + (lane << 2);
    #pragma unroll
    for (int hc=0; hc<8; ++hc){
      float4 pgv = *(const float4*)(part_cg + (size_t)hc*(Bq*Nq) + off);
      g.x += pgv.x; g.y += pgv.y; g.z += pgv.z; g.w += pgv.w;
    }
  }
  __syncthreads();
  int c0 = cq*128 + wave;
  const float* p = x + ((size_t)b*Cq + c0)*Nq + (nc << 8) + (lane << 2);
  float* pc = part_ch + ((size_t)(b*16 + nc) << 9) + c0;
  float4 acc = {0.f,0.f,0.f,0.f};
  #pragma unroll 8
  for (int k = 0; k < 32; ++k){
    float4 v = *(const float4*)(p + (size_t)(k*4)*Nq);
    float s = vs[wave + k*4];
    acc.x += v.x*s; acc.y += v.y*s; acc.z += v.z*s; acc.w += v.w*s;
    float r = v.x*g.x + v.y*g.y + v.z*g.z + v.w*g.w;
    #pragma unroll
    for (int off=32; off; off>>=1) r += __shfl_down(r, off, 64);
    if (lane == 0) pc[k*4] = r;
  }
  *(float4*)&red[wave][lane << 2] = acc;
  __syncthreads();
  part_sp[((size_t)(cq*Bq) + b)*Nq + (nc << 8) + t] =
      (red[0][t] + red[1][t]) + (red[2][t] + red[3][t]);
}

// ---------------------------------------------------------------------------
// K6' = k5 folded into k6 via REDUNDANT per-block softmax (no sync needed):
// 1024 blocks (b x 64 chunks of 8 c-rows). Each block reduces part_sp/part_ch
// (L2-resident, ~96KB) and computes both softmaxes in LDS — bitwise identical
// order to the old k5 — then writes its 8 out rows from LDS masks.
// Chunk-0 blocks additionally write the mask tail of out.
// ---------------------------------------------------------------------------
__global__ __launch_bounds__(256) void k6_fused(const float* __restrict__ x,
                                                const float* __restrict__ part_sp,
                                                const float* __restrict__ part_ch,
                                                float* __restrict__ out){
  __shared__ float buf[Nq];     // spatial comp -> spatial mask (in-place)
  __shared__ float chv[Cq];     // channel comp -> channel mask (in-place)
  __shared__ float lds4[4];
  __shared__ float bc;
  const size_t OUT0 = (size_t)Bq*Cq*Nq;
  int blk   = blockIdx.x;
  int b     = blk >> 6;
  int chunk = blk & 63;
  int t     = threadIdx.x;

  // ---- reduce partials into LDS ----
  for (int n = t; n < Nq; n += 256){
    float s = 0.f;
    #pragma unroll
    for (int q=0; q<4; ++q) s += part_sp[((size_t)(q*Bq)+b)*Nq + n];
    buf[n] = s;
  }
  for (int c = t; c < Cq; c += 256){
    float s = 0.f;
    #pragma unroll
    for (int q=0; q<16; ++q) s += part_ch[((size_t)(b*16+q) << 9) + c];
    chv[c] = s;
  }
  __syncthreads();

  // ---- spatial softmax over buf[0..4096) (k5-identical order) ----
  {
    float m = -3.4e38f;
    for (int i=t;i<Nq;i+=256) m = fmaxf(m, buf[i]);
    #pragma unroll
    for (int off=32; off; off>>=1) m = fmaxf(m, __shfl_down(m, off, 64));
    if ((t&63)==0) lds4[t>>6]=m;
    __syncthreads();
    if (t==0) bc = fmaxf(fmaxf(lds4[0],lds4[1]),fmaxf(lds4[2],lds4[3]));
    __syncthreads();
    m = bc;
    float ssum=0.f;
    for (int i=t;i<Nq;i+=256) ssum += __expf(buf[i]-m);
    #pragma unroll
    for (int off=32; off; off>>=1) ssum += __shfl_down(ssum, off, 64);
    __syncthreads();
    if ((t&63)==0) lds4[t>>6]=ssum;
    __syncthreads();
    if (t==0) bc = 1.f/((lds4[0]+lds4[1])+(lds4[2]+lds4[3]));
    __syncthreads();
    float inv = bc;
    for (int i=t;i<Nq;i+=256) buf[i] = __expf(buf[i]-m)*inv;   // sm in LDS
  }
  __syncthreads();
  // ---- channel softmax over chv[0..512) (k5-identical order) ----
  {
    float m = -3.4e38f;
    for (int i=t;i<Cq;i+=256) m = fmaxf(m, chv[i]);
    #pragma unroll
    for (int off=32; off; off>>=1) m = fmaxf(m, __shfl_down(m, off, 64));
    if ((t&63)==0) lds4[t>>6]=m;
    __syncthreads();
    if (t==0) bc = fmaxf(fmaxf(lds4[0],lds4[1]),fmaxf(lds4[2],lds4[3]));
    __syncthreads();
    m = bc;
    float ssum=0.f;
    for (int i=t;i<Cq;i+=256) ssum += __expf(chv[i]-m);
    #pragma unroll
    for (int off=32; off; off>>=1) ssum += __shfl_down(ssum, off, 64);
    __syncthreads();
    if ((t&63)==0) lds4[t>>6]=ssum;
    __syncthreads();
    if (t==0) bc = 1.f/((lds4[0]+lds4[1])+(lds4[2]+lds4[3]));
    __syncthreads();
    float inv = bc;
    for (int i=t;i<Cq;i+=256) chv[i] = __expf(chv[i]-m)*inv;   // cm in LDS
  }
  __syncthreads();

  // ---- chunk-0 block writes the mask tail ----
  if (chunk == 0){
    float* smd = out + OUT0 + (size_t)Bq*Cq + (size_t)b*Nq;
    for (int i=t;i<Nq;i+=256) smd[i] = buf[i];
    float* cmd = out + OUT0 + (size_t)b*Cq;
    for (int i=t;i<Cq;i+=256) cmd[i] = chv[i];
  }

  // ---- 8 output rows from LDS masks ----
  int cbase = chunk*8;
  int n0 = t*4;
  float4 sv0 = *(const float4*)&buf[n0];
  float4 sv1 = *(const float4*)&buf[n0 + 1024];
  float4 sv2 = *(const float4*)&buf[n0 + 2048];
  float4 sv3 = *(const float4*)&buf[n0 + 3072];
  #pragma unroll
  for (int r = 0; r < 8; ++r){
    int c = cbase + r;
    size_t ro = ((size_t)b*Cq + c)*Nq;
    float cmv = chv[c];
    float4 xv; f32x4 o;
    xv = *(const float4*)(x + ro + n0);
    o.x=xv.x*cmv*sv0.x; o.y=xv.y*cmv*sv0.y; o.z=xv.z*cmv*sv0.z; o.w=xv.w*cmv*sv0.w;
    __builtin_nontemporal_store(o, (f32x4*)(out + ro + n0));
    xv = *(const float4*)(x + ro + n0 + 1024);
    o.x=xv.x*cmv*sv1.x; o.y=xv.y*cmv*sv1.y; o.z=xv.z*cmv*sv1.z; o.w=xv.w*cmv*sv1.w;
    __builtin_nontemporal_store(o, (f32x4*)(out + ro + n0 + 1024));
    xv = *(const float4*)(x + ro + n0 + 2048);
    o.x=xv.x*cmv*sv2.x; o.y=xv.y*cmv*sv2.y; o.z=xv.z*cmv*sv2.z; o.w=xv.w*cmv*sv2.w;
    __builtin_nontemporal_store(o, (f32x4*)(out + ro + n0 + 2048));
    xv = *(const float4*)(x + ro + n0 + 3072);
    o.x=xv.x*cmv*sv3.x; o.y=xv.y*cmv*sv3.y; o.z=xv.z*cmv*sv3.z; o.w=xv.w*cmv*sv3.w;
    __builtin_nontemporal_store(o, (f32x4*)(out + ro + n0 + 3072));
  }
}

extern "C" void kernel_launch(void* const* d_in, const int* in_sizes, int n_in,
                              void* d_out, int out_size, void* d_ws, size_t ws_size,
                              hipStream_t stream){
  const float* x    = (const float*)d_in[0];
  const float* w_cf = (const float*)d_in[1];
  const float* w_cg = (const float*)d_in[2];
  const float* w_sf = (const float*)d_in[3];
  const float* w_sg = (const float*)d_in[4];
  float* out = (float*)d_out;

  float* ws = (float*)d_ws;
  float* xs_n = ws;                  // B*N
  float* xs_c = xs_n + Bq*Nq;        // B*C
  float* s_cf = xs_c + Bq*Cq;        // B*H
  float* s_sf = s_cf + Bq*Hq;        // B*H
  float* arenaA = s_sf + Bq*Hq;
  float* part_xs_n = arenaA;                    // 4*B*N  (k1 -> k1b)
  float* part_xs_c = arenaA + 4*Bq*Nq;          // 16*B*C (k1 -> k1b)
  float* part_cg   = arenaA;                    // 8*B*N  (k3 -> k4)
  float* part_sg   = arenaA + 8*Bq*Nq;          // 8*B*C  (k3 -> k4)
  float* arenaB = arenaA + 8*Bq*Nq + 8*Bq*Cq;
  float* part_sp   = arenaB;                    // 4*B*N  (k4 -> k6')
  float* part_ch   = arenaB + 4*Bq*Nq;          // 16*B*C (k4 -> k6')

  k1_stats<<<1024, 256, 0, stream>>>(x, part_xs_n, part_xs_c);
  k1b_red <<<288,  256, 0, stream>>>(part_xs_n, part_xs_c, xs_n, xs_c);
  k2_s    <<<2*Hq, 256, 0, stream>>>(w_cf, w_sf, xs_n, xs_c, s_cf, s_sf);
  k3_v    <<<144,  256, 0, stream>>>(w_cg, w_sg, s_cf, s_sf, part_cg, part_sg);
  k4_comp <<<1024, 256, 0, stream>>>(x, part_cg, part_sg, part_sp, part_ch);
  k6_fused<<<1024, 256, 0, stream>>>(x, part_sp, part_ch, out);
}